// Round 9
// baseline (453.935 us; speedup 1.0000x reference)
//
#include <hip/hip_runtime.h>
#include <hip/hip_bf16.h>

// ---------------------------------------------------------------------------
// VGAE forward: GraphConv(256->128)+ReLU, GraphConv(128->64) x2 (fused via
// linearity), reparameterize, then sigmoid(z @ z.T) via bf16 MFMA.
// N=16384 nodes, E=262144 edges, out = [pre (N*N), z (N*64)] fp32.
// R9: decoder stores transposed (symmetry) as dwordx4 (64 dword -> 16
// dwordx4 store instrs per wave-tile); 1024-thread scan. Rest = R8.
// ---------------------------------------------------------------------------

typedef short short8 __attribute__((ext_vector_type(8)));
typedef short short4v __attribute__((ext_vector_type(4)));
typedef float f32x4 __attribute__((ext_vector_type(4)));

__device__ __forceinline__ float bf2f(short s) {
  unsigned int u = ((unsigned int)(unsigned short)s) << 16;
  return __uint_as_float(u);
}
__device__ __forceinline__ short f2bf(float f) {
  __hip_bfloat16 h = __float2bfloat16(f);
  return *reinterpret_cast<short*>(&h);
}

__global__ void k_deg(const int* __restrict__ src, const int* __restrict__ dst,
                      float* __restrict__ cs, float* __restrict__ cd, int E) {
  int i = blockIdx.x * blockDim.x + threadIdx.x;
  if (i < E) {
    atomicAdd(&cs[src[i]], 1.0f);
    atomicAdd(&cd[dst[i]], 1.0f);
  }
}

// Exclusive prefix sum of in-degree counts -> off[0..n]. Single block,
// 1024 threads x 16 nodes each (n == 16384).
__global__ void __launch_bounds__(1024) k_scan(const float* __restrict__ cnt,
                                               int* __restrict__ off, int n) {
  __shared__ int sums[1024];
  const int t = threadIdx.x;
  const int per = n / 1024;
  const int base = t * per;
  int s = 0;
  for (int i = 0; i < per; ++i) s += (int)cnt[base + i];
  sums[t] = s;
  __syncthreads();
  for (int d = 1; d < 1024; d <<= 1) {
    int v = (t >= d) ? sums[t - d] : 0;
    __syncthreads();
    sums[t] += v;
    __syncthreads();
  }
  int run = t ? sums[t - 1] : 0;
  for (int i = 0; i < per; ++i) { off[base + i] = run; run += (int)cnt[base + i]; }
  if (t == 1023) off[n] = run;
}

__global__ void k_cnorm(float* __restrict__ cs, float* __restrict__ cd, int n) {
  int i = blockIdx.x * blockDim.x + threadIdx.x;
  if (i < n) {
    float a = cs[i]; cs[i] = (a > 0.f) ? rsqrtf(a) : 0.f;
    float b = cd[i]; cd[i] = (b > 0.f) ? rsqrtf(b) : 0.f;
  }
}

// elist[off[d] + pos] = src, grouped by dst.
__global__ void k_fill(const int* __restrict__ src, const int* __restrict__ dst,
                       const int* __restrict__ off, int* __restrict__ cursor,
                       int* __restrict__ elist, int E) {
  int e = blockIdx.x * blockDim.x + threadIdx.x;
  if (e < E) {
    int d = dst[e];
    int pos = atomicAdd(&cursor[d], 1);
    elist[off[d] + pos] = src[e];
  }
}

// Merged weight prep: blocks [0,128) -> W1 transpose-split, [128,192) -> W2.
__global__ void k_wprep(const float* __restrict__ W1, const float* __restrict__ Wm,
                        const float* __restrict__ Ws,
                        short* __restrict__ w1hi, short* __restrict__ w1lo,
                        short* __restrict__ w2hi, short* __restrict__ w2lo) {
  if (blockIdx.x < 128) {
    int idx = blockIdx.x * 256 + threadIdx.x;  // 32768
    int c = idx >> 8, k = idx & 255;
    float v = W1[k * 128 + c];
    short hb = f2bf(v);
    float hf = bf2f(hb);
    w1hi[c * 256 + k] = hb;
    w1lo[c * 256 + k] = f2bf(v - hf);
  } else {
    int idx = (blockIdx.x - 128) * 256 + threadIdx.x;  // 16384
    int c = idx >> 7, k = idx & 127;
    float v = (c < 64) ? Wm[k * 64 + c] : Ws[k * 64 + (c - 64)];
    short hb = f2bf(v);
    float hf = bf2f(hb);
    w2hi[c * 128 + k] = hb;
    w2lo[c * 128 + k] = f2bf(v - hf);
  }
}

// bufA = (x * cs) @ W1 via split-bf16 MFMA, output bf16. Block: 64 rows x
// 128 cols, 4 waves (32 cols each), K=256 in 8 steps of 32.
__global__ void __launch_bounds__(256) k_enc1(const float* __restrict__ x,
                                              const short* __restrict__ wt_hi,
                                              const short* __restrict__ wt_lo,
                                              const float* __restrict__ cs,
                                              __hip_bfloat16* __restrict__ out) {
  const int wave = threadIdx.x >> 6, lane = threadIdx.x & 63;
  const int lrow = lane & 15, kq = lane >> 4;
  const int brow = blockIdx.x * 64;
  const int bcol = wave * 32;

  f32x4 acc[4][2];
#pragma unroll
  for (int i = 0; i < 4; ++i)
#pragma unroll
    for (int j = 0; j < 2; ++j) acc[i][j] = (f32x4){0.f, 0.f, 0.f, 0.f};

  float crow[4];
#pragma unroll
  for (int i = 0; i < 4; ++i) crow[i] = cs[brow + i * 16 + lrow];

  for (int ks = 0; ks < 8; ++ks) {
    short8 ahi[4], alo[4];
#pragma unroll
    for (int i = 0; i < 4; ++i) {
      const float* ap = x + (size_t)(brow + i * 16 + lrow) * 256 + ks * 32 + kq * 8;
      f32x4 a0 = *reinterpret_cast<const f32x4*>(ap);
      f32x4 a1 = *reinterpret_cast<const f32x4*>(ap + 4);
      const float c = crow[i];
      float vals[8] = {a0.x, a0.y, a0.z, a0.w, a1.x, a1.y, a1.z, a1.w};
      short8 h, l;
#pragma unroll
      for (int j = 0; j < 8; ++j) {
        float v = vals[j] * c;
        short hb = f2bf(v);
        h[j] = hb;
        l[j] = f2bf(v - bf2f(hb));
      }
      ahi[i] = h; alo[i] = l;
    }
    short8 bhi[2], blo[2];
#pragma unroll
    for (int j = 0; j < 2; ++j) {
      size_t boff = (size_t)(bcol + j * 16 + lrow) * 256 + ks * 32 + kq * 8;
      bhi[j] = *reinterpret_cast<const short8*>(wt_hi + boff);
      blo[j] = *reinterpret_cast<const short8*>(wt_lo + boff);
    }
#pragma unroll
    for (int i = 0; i < 4; ++i)
#pragma unroll
      for (int j = 0; j < 2; ++j) {
        acc[i][j] = __builtin_amdgcn_mfma_f32_16x16x32_bf16(ahi[i], bhi[j], acc[i][j], 0, 0, 0);
        acc[i][j] = __builtin_amdgcn_mfma_f32_16x16x32_bf16(ahi[i], blo[j], acc[i][j], 0, 0, 0);
        acc[i][j] = __builtin_amdgcn_mfma_f32_16x16x32_bf16(alo[i], bhi[j], acc[i][j], 0, 0, 0);
      }
  }
#pragma unroll
  for (int i = 0; i < 4; ++i)
#pragma unroll
    for (int r = 0; r < 4; ++r) {
      int row = brow + i * 16 + kq * 4 + r;
#pragma unroll
      for (int j = 0; j < 2; ++j)
        out[(size_t)row * 128 + bcol + j * 16 + lrow] = __float2bfloat16(acc[i][j][r]);
    }
}

// Layer-1 CSR gather (bf16 table), R5 structure. 32 lanes/edge, 8B/lane,
// 2 edges/wave-iter. hs = bf16(relu(agg*cd + b1) * cs).
__global__ void __launch_bounds__(256) k_gather1(const short* __restrict__ tmp,
                                                 const int* __restrict__ off,
                                                 const int* __restrict__ elist,
                                                 const float* __restrict__ cd,
                                                 const float* __restrict__ cs,
                                                 const float* __restrict__ b,
                                                 short* __restrict__ hs) {
  const int node = blockIdx.x * 4 + (threadIdx.x >> 6);
  const int lane = threadIdx.x & 63;
  const int half = lane >> 5;
  const int c4 = (lane & 31) << 2;
  const int e0 = off[node], e1 = off[node + 1];
  f32x4 a = {0.f, 0.f, 0.f, 0.f};
  for (int e = e0 + half; e < e1; e += 2) {
    short4v v = *reinterpret_cast<const short4v*>(tmp + (size_t)elist[e] * 128 + c4);
    a.x += bf2f(v[0]); a.y += bf2f(v[1]); a.z += bf2f(v[2]); a.w += bf2f(v[3]);
  }
  a.x += __shfl_xor(a.x, 32);
  a.y += __shfl_xor(a.y, 32);
  a.z += __shfl_xor(a.z, 32);
  a.w += __shfl_xor(a.w, 32);
  if (half == 0) {
    const float c = cd[node], s = cs[node];
    f32x4 bb = *reinterpret_cast<const f32x4*>(b + c4);
    short4v r;
    r[0] = f2bf(fmaxf(a.x * c + bb.x, 0.f) * s);
    r[1] = f2bf(fmaxf(a.y * c + bb.y, 0.f) * s);
    r[2] = f2bf(fmaxf(a.z * c + bb.z, 0.f) * s);
    r[3] = f2bf(fmaxf(a.w * c + bb.w, 0.f) * s);
    *reinterpret_cast<short4v*>(hs + (size_t)node * 128 + c4) = r;
  }
}

// Layer-2/3 shared aggregation: s2c[node] = cd[node] * sum_{src} hs[src].
__global__ void __launch_bounds__(256) k_gather2(const short* __restrict__ hs,
                                                 const int* __restrict__ off,
                                                 const int* __restrict__ elist,
                                                 const float* __restrict__ cd,
                                                 float* __restrict__ s2c) {
  const int node = blockIdx.x * 4 + (threadIdx.x >> 6);
  const int lane = threadIdx.x & 63;
  const int half = lane >> 5;
  const int c4 = (lane & 31) << 2;
  const int e0 = off[node], e1 = off[node + 1];
  f32x4 a = {0.f, 0.f, 0.f, 0.f};
  for (int e = e0 + half; e < e1; e += 2) {
    short4v v = *reinterpret_cast<const short4v*>(hs + (size_t)elist[e] * 128 + c4);
    a.x += bf2f(v[0]); a.y += bf2f(v[1]); a.z += bf2f(v[2]); a.w += bf2f(v[3]);
  }
  a.x += __shfl_xor(a.x, 32);
  a.y += __shfl_xor(a.y, 32);
  a.z += __shfl_xor(a.z, 32);
  a.w += __shfl_xor(a.w, 32);
  if (half == 0) {
    const float c = cd[node];
    *reinterpret_cast<f32x4*>(s2c + (size_t)node * 128 + c4) = a * c;
  }
}

// z-finish via split-bf16 MFMA: ys = s2c @ [Wm|Ws] + [bm|bs], then
// z = ys[:, :64] + noise * exp(ys[:, 64:]); also bf16 copy of z.
__global__ void __launch_bounds__(256) k_zfin2(const float* __restrict__ s2c,
                                               const short* __restrict__ wt_hi,
                                               const short* __restrict__ wt_lo,
                                               const float* __restrict__ bm,
                                               const float* __restrict__ bs,
                                               const float* __restrict__ noise,
                                               float* __restrict__ z,
                                               __hip_bfloat16* __restrict__ zb) {
  __shared__ float ys[64][128];
  const int wave = threadIdx.x >> 6, lane = threadIdx.x & 63;
  const int lrow = lane & 15, kq = lane >> 4;
  const int brow = blockIdx.x * 64;
  const int bcol = wave * 32;

  f32x4 acc[4][2];
#pragma unroll
  for (int i = 0; i < 4; ++i)
#pragma unroll
    for (int j = 0; j < 2; ++j) acc[i][j] = (f32x4){0.f, 0.f, 0.f, 0.f};

  for (int ks = 0; ks < 4; ++ks) {
    short8 ahi[4], alo[4];
#pragma unroll
    for (int i = 0; i < 4; ++i) {
      const float* ap = s2c + (size_t)(brow + i * 16 + lrow) * 128 + ks * 32 + kq * 8;
      f32x4 a0 = *reinterpret_cast<const f32x4*>(ap);
      f32x4 a1 = *reinterpret_cast<const f32x4*>(ap + 4);
      float vals[8] = {a0.x, a0.y, a0.z, a0.w, a1.x, a1.y, a1.z, a1.w};
      short8 h, l;
#pragma unroll
      for (int j = 0; j < 8; ++j) {
        float v = vals[j];
        short hb = f2bf(v);
        h[j] = hb;
        l[j] = f2bf(v - bf2f(hb));
      }
      ahi[i] = h; alo[i] = l;
    }
    short8 bhi[2], blo[2];
#pragma unroll
    for (int j = 0; j < 2; ++j) {
      size_t boff = (size_t)(bcol + j * 16 + lrow) * 128 + ks * 32 + kq * 8;
      bhi[j] = *reinterpret_cast<const short8*>(wt_hi + boff);
      blo[j] = *reinterpret_cast<const short8*>(wt_lo + boff);
    }
#pragma unroll
    for (int i = 0; i < 4; ++i)
#pragma unroll
      for (int j = 0; j < 2; ++j) {
        acc[i][j] = __builtin_amdgcn_mfma_f32_16x16x32_bf16(ahi[i], bhi[j], acc[i][j], 0, 0, 0);
        acc[i][j] = __builtin_amdgcn_mfma_f32_16x16x32_bf16(ahi[i], blo[j], acc[i][j], 0, 0, 0);
        acc[i][j] = __builtin_amdgcn_mfma_f32_16x16x32_bf16(alo[i], bhi[j], acc[i][j], 0, 0, 0);
      }
  }
#pragma unroll
  for (int j = 0; j < 2; ++j) {
    const int col = bcol + j * 16 + lrow;
    const float bias = (col < 64) ? bm[col] : bs[col - 64];
#pragma unroll
    for (int i = 0; i < 4; ++i)
#pragma unroll
      for (int r = 0; r < 4; ++r)
        ys[i * 16 + kq * 4 + r][col] = acc[i][j][r] + bias;
  }
  __syncthreads();
  const int t = threadIdx.x;
#pragma unroll
  for (int q = 0; q < 16; ++q) {
    int idx = t + 256 * q;  // 0..4095
    int row = idx >> 6, c = idx & 63;
    float m = ys[row][c], ls = ys[row][c + 64];
    float zv = m + noise[(size_t)(brow + row) * 64 + c] * __expf(ls);
    z[(size_t)(brow + row) * 64 + c]  = zv;
    zb[(size_t)(brow + row) * 64 + c] = __float2bfloat16(zv);
  }
}

// pre[i,j] = sigmoid(dot(z[i,:], z[j,:])) via mfma_f32_16x16x32_bf16.
// pre is symmetric -> store each lane's 4 accs (4 consecutive ROWS, one col
// in C layout) TRANSPOSED as one dwordx4 (4 consecutive cols, one row):
// 16 global_store_dwordx4 per wave-tile instead of 64 global_store_dword.
__global__ void __launch_bounds__(256) k_zz_mfma(const short* __restrict__ zb,
                                                 float* __restrict__ pre, int n) {
  const int wave = threadIdx.x >> 6, lane = threadIdx.x & 63;
  const int wr = wave >> 1, wc = wave & 1;
  const int brow = blockIdx.y * 128 + wr * 64;
  const int bcol = blockIdx.x * 128 + wc * 64;
  const int lrow = lane & 15;
  const int kq = lane >> 4;

  short8 afrag[2][4], bfrag[2][4];
#pragma unroll
  for (int tt = 0; tt < 4; ++tt) {
#pragma unroll
    for (int ks = 0; ks < 2; ++ks) {
      afrag[ks][tt] = *reinterpret_cast<const short8*>(
          zb + (size_t)(brow + tt * 16 + lrow) * 64 + ks * 32 + kq * 8);
      bfrag[ks][tt] = *reinterpret_cast<const short8*>(
          zb + (size_t)(bcol + tt * 16 + lrow) * 64 + ks * 32 + kq * 8);
    }
  }

  f32x4 acc[4][4];
#pragma unroll
  for (int i = 0; i < 4; ++i)
#pragma unroll
    for (int j = 0; j < 4; ++j) acc[i][j] = (f32x4){0.f, 0.f, 0.f, 0.f};

#pragma unroll
  for (int i = 0; i < 4; ++i)
#pragma unroll
    for (int j = 0; j < 4; ++j) {
      acc[i][j] = __builtin_amdgcn_mfma_f32_16x16x32_bf16(afrag[0][i], bfrag[0][j], acc[i][j], 0, 0, 0);
      acc[i][j] = __builtin_amdgcn_mfma_f32_16x16x32_bf16(afrag[1][i], bfrag[1][j], acc[i][j], 0, 0, 0);
    }

  const int crow0 = kq * 4;
#pragma unroll
  for (int i = 0; i < 4; ++i) {
#pragma unroll
    for (int j = 0; j < 4; ++j) {
      f32x4 o;
#pragma unroll
      for (int r = 0; r < 4; ++r) {
        float e = __expf(-acc[i][j][r]);
        o[r] = __builtin_amdgcn_rcpf(1.f + e);
      }
      // logical entry (brow+i*16+crow0+r, bcol+j*16+lrow) stored transposed
      size_t row = (size_t)(bcol + j * 16 + lrow);
      *reinterpret_cast<f32x4*>(&pre[row * (size_t)n + brow + i * 16 + crow0]) = o;
    }
  }
}

extern "C" void kernel_launch(void* const* d_in, const int* in_sizes, int n_in,
                              void* d_out, int out_size, void* d_ws, size_t ws_size,
                              hipStream_t stream) {
  const float* feat  = (const float*)d_in[0];
  const float* W1    = (const float*)d_in[1];
  const float* b1    = (const float*)d_in[2];
  const float* Wm    = (const float*)d_in[3];
  const float* bm    = (const float*)d_in[4];
  const float* Ws    = (const float*)d_in[5];
  const float* bs    = (const float*)d_in[6];
  const float* noise = (const float*)d_in[7];
  const int* esrc    = (const int*)d_in[8];
  const int* edst    = (const int*)d_in[9];

  const int N = in_sizes[0] / 256;   // 16384
  const int E = in_sizes[8];         // 262144

  float* out = (float*)d_out;
  float* z   = out + (size_t)N * N;  // z lives in d_out after pre

  char* ws = (char*)d_ws;
  float* c_src  = (float*)(ws + 0);                 // [N]
  float* c_dst  = (float*)(ws + 65536);             // [N]
  int*   cursor = (int*)  (ws + 131072);            // [N]
  int*   off    = (int*)  (ws + 196608);            // [N+1]
  int*   elist  = (int*)  (ws + 327680);            // [E] -> ends 1376256
  short* w1t_hi = (short*)(ws + 1376256);           // [128][256]
  short* w1t_lo = (short*)(ws + 1441792);
  short* w2t_hi = (short*)(ws + 1507328);           // [128][128]
  short* w2t_lo = (short*)(ws + 1540096);           // ends 1572864
  short* bufA   = (short*)(ws + 2097152);           // [N][128] bf16 xw1 out
  short* hsb    = (short*)(ws + 6291456);           // [N][128] bf16 relu(h)*cs
  float* s2c    = (float*)(ws + 10485760);          // [N][128] fp32
  __hip_bfloat16* zb = (__hip_bfloat16*)(ws + 18874368);  // [N,64] bf16 z

  // weight prep (independent of graph build)
  k_wprep<<<192, 256, 0, stream>>>(W1, Wm, Ws, w1t_hi, w1t_lo, w2t_hi, w2t_lo);

  // degree counts + CSR offsets + norms + edge lists
  hipMemsetAsync(ws, 0, 196608, stream);  // c_src, c_dst, cursor
  k_deg<<<(E + 255) / 256, 256, 0, stream>>>(esrc, edst, c_src, c_dst, E);
  k_scan<<<1, 1024, 0, stream>>>(c_dst, off, N);
  k_cnorm<<<(N + 255) / 256, 256, 0, stream>>>(c_src, c_dst, N);
  k_fill<<<(E + 255) / 256, 256, 0, stream>>>(esrc, edst, off, cursor, elist, E);

  // layer 1: bufA = bf16((x*cs)@W1) ; gather -> hsb = bf16(relu(agg*cd+b1)*cs)
  k_enc1<<<N / 64, 256, 0, stream>>>(feat, w1t_hi, w1t_lo, c_src, (__hip_bfloat16*)bufA);
  k_gather1<<<N / 4, 256, 0, stream>>>(bufA, off, elist, c_dst, c_src, b1, hsb);

  // layers 2+3: s2c = cd * agg(hsb) ; z = GEMM + reparam
  k_gather2<<<N / 4, 256, 0, stream>>>(hsb, off, elist, c_dst, s2c);
  k_zfin2<<<N / 64, 256, 0, stream>>>(s2c, w2t_hi, w2t_lo, bm, bs, noise, z, zb);

  // decoder: pre = sigmoid(z @ z.T), bf16 MFMA, transposed dwordx4 stores
  dim3 zgrid(N / 128, N / 128);
  k_zz_mfma<<<zgrid, 256, 0, stream>>>((const short*)zb, out, N);
}

// Round 10
// 398.266 us; speedup vs baseline: 1.1398x; 1.1398x over previous
//
#include <hip/hip_runtime.h>
#include <hip/hip_bf16.h>

// ---------------------------------------------------------------------------
// VGAE forward: GraphConv(256->128)+ReLU, GraphConv(128->64) x2 (fused via
// linearity), reparameterize, then sigmoid(z @ z.T) via bf16 MFMA.
// N=16384 nodes, E=262144 edges, out = [pre (N*N), z (N*64)] fp32.
// R10: R8 base (best: 371.6us) + per-wave LDS-staged decoder epilogue ->
// fully coalesced 256B-contiguous dwordx4 stores (segments/tile 256 -> 64).
// R9 transposed stores + 1024-scan reverted (regression +82us).
// ---------------------------------------------------------------------------

typedef short short8 __attribute__((ext_vector_type(8)));
typedef short short4v __attribute__((ext_vector_type(4)));
typedef float f32x4 __attribute__((ext_vector_type(4)));

__device__ __forceinline__ float bf2f(short s) {
  unsigned int u = ((unsigned int)(unsigned short)s) << 16;
  return __uint_as_float(u);
}
__device__ __forceinline__ short f2bf(float f) {
  __hip_bfloat16 h = __float2bfloat16(f);
  return *reinterpret_cast<short*>(&h);
}

__global__ void k_deg(const int* __restrict__ src, const int* __restrict__ dst,
                      float* __restrict__ cs, float* __restrict__ cd, int E) {
  int i = blockIdx.x * blockDim.x + threadIdx.x;
  if (i < E) {
    atomicAdd(&cs[src[i]], 1.0f);
    atomicAdd(&cd[dst[i]], 1.0f);
  }
}

// Exclusive prefix sum of in-degree counts -> off[0..n]. Single block.
__global__ void __launch_bounds__(256) k_scan(const float* __restrict__ cnt,
                                              int* __restrict__ off, int n) {
  __shared__ int sums[256];
  const int t = threadIdx.x;
  const int per = n / 256;
  const int base = t * per;
  int s = 0;
  for (int i = 0; i < per; ++i) s += (int)cnt[base + i];
  sums[t] = s;
  __syncthreads();
  for (int d = 1; d < 256; d <<= 1) {
    int v = (t >= d) ? sums[t - d] : 0;
    __syncthreads();
    sums[t] += v;
    __syncthreads();
  }
  int run = t ? sums[t - 1] : 0;
  for (int i = 0; i < per; ++i) { off[base + i] = run; run += (int)cnt[base + i]; }
  if (t == 255) off[n] = run;
}

__global__ void k_cnorm(float* __restrict__ cs, float* __restrict__ cd, int n) {
  int i = blockIdx.x * blockDim.x + threadIdx.x;
  if (i < n) {
    float a = cs[i]; cs[i] = (a > 0.f) ? rsqrtf(a) : 0.f;
    float b = cd[i]; cd[i] = (b > 0.f) ? rsqrtf(b) : 0.f;
  }
}

// elist[off[d] + pos] = src, grouped by dst.
__global__ void k_fill(const int* __restrict__ src, const int* __restrict__ dst,
                       const int* __restrict__ off, int* __restrict__ cursor,
                       int* __restrict__ elist, int E) {
  int e = blockIdx.x * blockDim.x + threadIdx.x;
  if (e < E) {
    int d = dst[e];
    int pos = atomicAdd(&cursor[d], 1);
    elist[off[d] + pos] = src[e];
  }
}

// Merged weight prep: blocks [0,128) -> W1 transpose-split, [128,192) -> W2.
__global__ void k_wprep(const float* __restrict__ W1, const float* __restrict__ Wm,
                        const float* __restrict__ Ws,
                        short* __restrict__ w1hi, short* __restrict__ w1lo,
                        short* __restrict__ w2hi, short* __restrict__ w2lo) {
  if (blockIdx.x < 128) {
    int idx = blockIdx.x * 256 + threadIdx.x;  // 32768
    int c = idx >> 8, k = idx & 255;
    float v = W1[k * 128 + c];
    short hb = f2bf(v);
    float hf = bf2f(hb);
    w1hi[c * 256 + k] = hb;
    w1lo[c * 256 + k] = f2bf(v - hf);
  } else {
    int idx = (blockIdx.x - 128) * 256 + threadIdx.x;  // 16384
    int c = idx >> 7, k = idx & 127;
    float v = (c < 64) ? Wm[k * 64 + c] : Ws[k * 64 + (c - 64)];
    short hb = f2bf(v);
    float hf = bf2f(hb);
    w2hi[c * 128 + k] = hb;
    w2lo[c * 128 + k] = f2bf(v - hf);
  }
}

// bufA = (x * cs) @ W1 via split-bf16 MFMA, output bf16. Block: 64 rows x
// 128 cols, 4 waves (32 cols each), K=256 in 8 steps of 32.
__global__ void __launch_bounds__(256) k_enc1(const float* __restrict__ x,
                                              const short* __restrict__ wt_hi,
                                              const short* __restrict__ wt_lo,
                                              const float* __restrict__ cs,
                                              __hip_bfloat16* __restrict__ out) {
  const int wave = threadIdx.x >> 6, lane = threadIdx.x & 63;
  const int lrow = lane & 15, kq = lane >> 4;
  const int brow = blockIdx.x * 64;
  const int bcol = wave * 32;

  f32x4 acc[4][2];
#pragma unroll
  for (int i = 0; i < 4; ++i)
#pragma unroll
    for (int j = 0; j < 2; ++j) acc[i][j] = (f32x4){0.f, 0.f, 0.f, 0.f};

  float crow[4];
#pragma unroll
  for (int i = 0; i < 4; ++i) crow[i] = cs[brow + i * 16 + lrow];

  for (int ks = 0; ks < 8; ++ks) {
    short8 ahi[4], alo[4];
#pragma unroll
    for (int i = 0; i < 4; ++i) {
      const float* ap = x + (size_t)(brow + i * 16 + lrow) * 256 + ks * 32 + kq * 8;
      f32x4 a0 = *reinterpret_cast<const f32x4*>(ap);
      f32x4 a1 = *reinterpret_cast<const f32x4*>(ap + 4);
      const float c = crow[i];
      float vals[8] = {a0.x, a0.y, a0.z, a0.w, a1.x, a1.y, a1.z, a1.w};
      short8 h, l;
#pragma unroll
      for (int j = 0; j < 8; ++j) {
        float v = vals[j] * c;
        short hb = f2bf(v);
        h[j] = hb;
        l[j] = f2bf(v - bf2f(hb));
      }
      ahi[i] = h; alo[i] = l;
    }
    short8 bhi[2], blo[2];
#pragma unroll
    for (int j = 0; j < 2; ++j) {
      size_t boff = (size_t)(bcol + j * 16 + lrow) * 256 + ks * 32 + kq * 8;
      bhi[j] = *reinterpret_cast<const short8*>(wt_hi + boff);
      blo[j] = *reinterpret_cast<const short8*>(wt_lo + boff);
    }
#pragma unroll
    for (int i = 0; i < 4; ++i)
#pragma unroll
      for (int j = 0; j < 2; ++j) {
        acc[i][j] = __builtin_amdgcn_mfma_f32_16x16x32_bf16(ahi[i], bhi[j], acc[i][j], 0, 0, 0);
        acc[i][j] = __builtin_amdgcn_mfma_f32_16x16x32_bf16(ahi[i], blo[j], acc[i][j], 0, 0, 0);
        acc[i][j] = __builtin_amdgcn_mfma_f32_16x16x32_bf16(alo[i], bhi[j], acc[i][j], 0, 0, 0);
      }
  }
#pragma unroll
  for (int i = 0; i < 4; ++i)
#pragma unroll
    for (int r = 0; r < 4; ++r) {
      int row = brow + i * 16 + kq * 4 + r;
#pragma unroll
      for (int j = 0; j < 2; ++j)
        out[(size_t)row * 128 + bcol + j * 16 + lrow] = __float2bfloat16(acc[i][j][r]);
    }
}

// Layer-1 CSR gather (bf16 table), R5 structure. 32 lanes/edge, 8B/lane,
// 2 edges/wave-iter. hs = bf16(relu(agg*cd + b1) * cs).
__global__ void __launch_bounds__(256) k_gather1(const short* __restrict__ tmp,
                                                 const int* __restrict__ off,
                                                 const int* __restrict__ elist,
                                                 const float* __restrict__ cd,
                                                 const float* __restrict__ cs,
                                                 const float* __restrict__ b,
                                                 short* __restrict__ hs) {
  const int node = blockIdx.x * 4 + (threadIdx.x >> 6);
  const int lane = threadIdx.x & 63;
  const int half = lane >> 5;
  const int c4 = (lane & 31) << 2;
  const int e0 = off[node], e1 = off[node + 1];
  f32x4 a = {0.f, 0.f, 0.f, 0.f};
  for (int e = e0 + half; e < e1; e += 2) {
    short4v v = *reinterpret_cast<const short4v*>(tmp + (size_t)elist[e] * 128 + c4);
    a.x += bf2f(v[0]); a.y += bf2f(v[1]); a.z += bf2f(v[2]); a.w += bf2f(v[3]);
  }
  a.x += __shfl_xor(a.x, 32);
  a.y += __shfl_xor(a.y, 32);
  a.z += __shfl_xor(a.z, 32);
  a.w += __shfl_xor(a.w, 32);
  if (half == 0) {
    const float c = cd[node], s = cs[node];
    f32x4 bb = *reinterpret_cast<const f32x4*>(b + c4);
    short4v r;
    r[0] = f2bf(fmaxf(a.x * c + bb.x, 0.f) * s);
    r[1] = f2bf(fmaxf(a.y * c + bb.y, 0.f) * s);
    r[2] = f2bf(fmaxf(a.z * c + bb.z, 0.f) * s);
    r[3] = f2bf(fmaxf(a.w * c + bb.w, 0.f) * s);
    *reinterpret_cast<short4v*>(hs + (size_t)node * 128 + c4) = r;
  }
}

// Layer-2/3 shared aggregation: s2c[node] = cd[node] * sum_{src} hs[src].
__global__ void __launch_bounds__(256) k_gather2(const short* __restrict__ hs,
                                                 const int* __restrict__ off,
                                                 const int* __restrict__ elist,
                                                 const float* __restrict__ cd,
                                                 float* __restrict__ s2c) {
  const int node = blockIdx.x * 4 + (threadIdx.x >> 6);
  const int lane = threadIdx.x & 63;
  const int half = lane >> 5;
  const int c4 = (lane & 31) << 2;
  const int e0 = off[node], e1 = off[node + 1];
  f32x4 a = {0.f, 0.f, 0.f, 0.f};
  for (int e = e0 + half; e < e1; e += 2) {
    short4v v = *reinterpret_cast<const short4v*>(hs + (size_t)elist[e] * 128 + c4);
    a.x += bf2f(v[0]); a.y += bf2f(v[1]); a.z += bf2f(v[2]); a.w += bf2f(v[3]);
  }
  a.x += __shfl_xor(a.x, 32);
  a.y += __shfl_xor(a.y, 32);
  a.z += __shfl_xor(a.z, 32);
  a.w += __shfl_xor(a.w, 32);
  if (half == 0) {
    const float c = cd[node];
    *reinterpret_cast<f32x4*>(s2c + (size_t)node * 128 + c4) = a * c;
  }
}

// z-finish via split-bf16 MFMA: ys = s2c @ [Wm|Ws] + [bm|bs], then
// z = ys[:, :64] + noise * exp(ys[:, 64:]); also bf16 copy of z.
__global__ void __launch_bounds__(256) k_zfin2(const float* __restrict__ s2c,
                                               const short* __restrict__ wt_hi,
                                               const short* __restrict__ wt_lo,
                                               const float* __restrict__ bm,
                                               const float* __restrict__ bs,
                                               const float* __restrict__ noise,
                                               float* __restrict__ z,
                                               __hip_bfloat16* __restrict__ zb) {
  __shared__ float ys[64][128];
  const int wave = threadIdx.x >> 6, lane = threadIdx.x & 63;
  const int lrow = lane & 15, kq = lane >> 4;
  const int brow = blockIdx.x * 64;
  const int bcol = wave * 32;

  f32x4 acc[4][2];
#pragma unroll
  for (int i = 0; i < 4; ++i)
#pragma unroll
    for (int j = 0; j < 2; ++j) acc[i][j] = (f32x4){0.f, 0.f, 0.f, 0.f};

  for (int ks = 0; ks < 4; ++ks) {
    short8 ahi[4], alo[4];
#pragma unroll
    for (int i = 0; i < 4; ++i) {
      const float* ap = s2c + (size_t)(brow + i * 16 + lrow) * 128 + ks * 32 + kq * 8;
      f32x4 a0 = *reinterpret_cast<const f32x4*>(ap);
      f32x4 a1 = *reinterpret_cast<const f32x4*>(ap + 4);
      float vals[8] = {a0.x, a0.y, a0.z, a0.w, a1.x, a1.y, a1.z, a1.w};
      short8 h, l;
#pragma unroll
      for (int j = 0; j < 8; ++j) {
        float v = vals[j];
        short hb = f2bf(v);
        h[j] = hb;
        l[j] = f2bf(v - bf2f(hb));
      }
      ahi[i] = h; alo[i] = l;
    }
    short8 bhi[2], blo[2];
#pragma unroll
    for (int j = 0; j < 2; ++j) {
      size_t boff = (size_t)(bcol + j * 16 + lrow) * 128 + ks * 32 + kq * 8;
      bhi[j] = *reinterpret_cast<const short8*>(wt_hi + boff);
      blo[j] = *reinterpret_cast<const short8*>(wt_lo + boff);
    }
#pragma unroll
    for (int i = 0; i < 4; ++i)
#pragma unroll
      for (int j = 0; j < 2; ++j) {
        acc[i][j] = __builtin_amdgcn_mfma_f32_16x16x32_bf16(ahi[i], bhi[j], acc[i][j], 0, 0, 0);
        acc[i][j] = __builtin_amdgcn_mfma_f32_16x16x32_bf16(ahi[i], blo[j], acc[i][j], 0, 0, 0);
        acc[i][j] = __builtin_amdgcn_mfma_f32_16x16x32_bf16(alo[i], bhi[j], acc[i][j], 0, 0, 0);
      }
  }
#pragma unroll
  for (int j = 0; j < 2; ++j) {
    const int col = bcol + j * 16 + lrow;
    const float bias = (col < 64) ? bm[col] : bs[col - 64];
#pragma unroll
    for (int i = 0; i < 4; ++i)
#pragma unroll
      for (int r = 0; r < 4; ++r)
        ys[i * 16 + kq * 4 + r][col] = acc[i][j][r] + bias;
  }
  __syncthreads();
  const int t = threadIdx.x;
#pragma unroll
  for (int q = 0; q < 16; ++q) {
    int idx = t + 256 * q;  // 0..4095
    int row = idx >> 6, c = idx & 63;
    float m = ys[row][c], ls = ys[row][c + 64];
    float zv = m + noise[(size_t)(brow + row) * 64 + c] * __expf(ls);
    z[(size_t)(brow + row) * 64 + c]  = zv;
    zb[(size_t)(brow + row) * 64 + c] = __float2bfloat16(zv);
  }
}

// pre[i,j] = sigmoid(dot(z[i,:], z[j,:])) via mfma_f32_16x16x32_bf16.
// Epilogue: per-wave LDS staging (stride 65 dwords, conflict-free b128
// reads), then 16 dwordx4 stores/wave, each 4 rows x 256B CONTIGUOUS.
__global__ void __launch_bounds__(256) k_zz_mfma(const short* __restrict__ zb,
                                                 float* __restrict__ pre, int n) {
  __shared__ float stg[4][64 * 65];
  const int wave = threadIdx.x >> 6, lane = threadIdx.x & 63;
  const int wr = wave >> 1, wc = wave & 1;
  const int brow = blockIdx.y * 128 + wr * 64;
  const int bcol = blockIdx.x * 128 + wc * 64;
  const int lrow = lane & 15;
  const int kq = lane >> 4;

  short8 afrag[2][4], bfrag[2][4];
#pragma unroll
  for (int tt = 0; tt < 4; ++tt) {
#pragma unroll
    for (int ks = 0; ks < 2; ++ks) {
      afrag[ks][tt] = *reinterpret_cast<const short8*>(
          zb + (size_t)(brow + tt * 16 + lrow) * 64 + ks * 32 + kq * 8);
      bfrag[ks][tt] = *reinterpret_cast<const short8*>(
          zb + (size_t)(bcol + tt * 16 + lrow) * 64 + ks * 32 + kq * 8);
    }
  }

  f32x4 acc[4][4];
#pragma unroll
  for (int i = 0; i < 4; ++i)
#pragma unroll
    for (int j = 0; j < 4; ++j) acc[i][j] = (f32x4){0.f, 0.f, 0.f, 0.f};

#pragma unroll
  for (int i = 0; i < 4; ++i)
#pragma unroll
    for (int j = 0; j < 4; ++j) {
      acc[i][j] = __builtin_amdgcn_mfma_f32_16x16x32_bf16(afrag[0][i], bfrag[0][j], acc[i][j], 0, 0, 0);
      acc[i][j] = __builtin_amdgcn_mfma_f32_16x16x32_bf16(afrag[1][i], bfrag[1][j], acc[i][j], 0, 0, 0);
    }

  // stage sigmoid(acc) into per-wave LDS tile [64 rows][65 dword stride]
  float* my = stg[wave];
  const int crow0 = kq * 4;
#pragma unroll
  for (int i = 0; i < 4; ++i)
#pragma unroll
    for (int j = 0; j < 4; ++j)
#pragma unroll
      for (int r = 0; r < 4; ++r) {
        float e = __expf(-acc[i][j][r]);
        my[(i * 16 + crow0 + r) * 65 + j * 16 + lrow] = __builtin_amdgcn_rcpf(1.f + e);
      }
  __syncthreads();
  // coalesced store: instr m covers rows m*4+hi (4 rows) x 256B contiguous
  const int hi4 = lane >> 4, lo = lane & 15;
#pragma unroll
  for (int m = 0; m < 16; ++m) {
    int row = m * 4 + hi4;
    f32x4 v = *reinterpret_cast<const f32x4*>(&my[row * 65 + lo * 4]);
    *reinterpret_cast<f32x4*>(&pre[(size_t)(brow + row) * n + bcol + lo * 4]) = v;
  }
}

extern "C" void kernel_launch(void* const* d_in, const int* in_sizes, int n_in,
                              void* d_out, int out_size, void* d_ws, size_t ws_size,
                              hipStream_t stream) {
  const float* feat  = (const float*)d_in[0];
  const float* W1    = (const float*)d_in[1];
  const float* b1    = (const float*)d_in[2];
  const float* Wm    = (const float*)d_in[3];
  const float* bm    = (const float*)d_in[4];
  const float* Ws    = (const float*)d_in[5];
  const float* bs    = (const float*)d_in[6];
  const float* noise = (const float*)d_in[7];
  const int* esrc    = (const int*)d_in[8];
  const int* edst    = (const int*)d_in[9];

  const int N = in_sizes[0] / 256;   // 16384
  const int E = in_sizes[8];         // 262144

  float* out = (float*)d_out;
  float* z   = out + (size_t)N * N;  // z lives in d_out after pre

  char* ws = (char*)d_ws;
  float* c_src  = (float*)(ws + 0);                 // [N]
  float* c_dst  = (float*)(ws + 65536);             // [N]
  int*   cursor = (int*)  (ws + 131072);            // [N]
  int*   off    = (int*)  (ws + 196608);            // [N+1]
  int*   elist  = (int*)  (ws + 327680);            // [E] -> ends 1376256
  short* w1t_hi = (short*)(ws + 1376256);           // [128][256]
  short* w1t_lo = (short*)(ws + 1441792);
  short* w2t_hi = (short*)(ws + 1507328);           // [128][128]
  short* w2t_lo = (short*)(ws + 1540096);           // ends 1572864
  short* bufA   = (short*)(ws + 2097152);           // [N][128] bf16 xw1 out
  short* hsb    = (short*)(ws + 6291456);           // [N][128] bf16 relu(h)*cs
  float* s2c    = (float*)(ws + 10485760);          // [N][128] fp32
  __hip_bfloat16* zb = (__hip_bfloat16*)(ws + 18874368);  // [N,64] bf16 z

  // weight prep (independent of graph build)
  k_wprep<<<192, 256, 0, stream>>>(W1, Wm, Ws, w1t_hi, w1t_lo, w2t_hi, w2t_lo);

  // degree counts + CSR offsets + norms + edge lists
  hipMemsetAsync(ws, 0, 196608, stream);  // c_src, c_dst, cursor
  k_deg<<<(E + 255) / 256, 256, 0, stream>>>(esrc, edst, c_src, c_dst, E);
  k_scan<<<1, 256, 0, stream>>>(c_dst, off, N);
  k_cnorm<<<(N + 255) / 256, 256, 0, stream>>>(c_src, c_dst, N);
  k_fill<<<(E + 255) / 256, 256, 0, stream>>>(esrc, edst, off, cursor, elist, E);

  // layer 1: bufA = bf16((x*cs)@W1) ; gather -> hsb = bf16(relu(agg*cd+b1)*cs)
  k_enc1<<<N / 64, 256, 0, stream>>>(feat, w1t_hi, w1t_lo, c_src, (__hip_bfloat16*)bufA);
  k_gather1<<<N / 4, 256, 0, stream>>>(bufA, off, elist, c_dst, c_src, b1, hsb);

  // layers 2+3: s2c = cd * agg(hsb) ; z = GEMM + reparam
  k_gather2<<<N / 4, 256, 0, stream>>>(hsb, off, elist, c_dst, s2c);
  k_zfin2<<<N / 64, 256, 0, stream>>>(s2c, w2t_hi, w2t_lo, bm, bs, noise, z, zb);

  // decoder: pre = sigmoid(z @ z.T), bf16 MFMA, LDS-staged coalesced stores
  dim3 zgrid(N / 128, N / 128);
  k_zz_mfma<<<zgrid, 256, 0, stream>>>((const short*)zb, out, N);
}

// Round 11
// 368.032 us; speedup vs baseline: 1.2334x; 1.0821x over previous
//
#include <hip/hip_runtime.h>
#include <hip/hip_bf16.h>

// ---------------------------------------------------------------------------
// VGAE forward: GraphConv(256->128)+ReLU, GraphConv(128->64) x2 (fused via
// linearity), reparameterize, then sigmoid(z @ z.T) via bf16 MFMA.
// N=16384 nodes, E=262144 edges, out = [pre (N*N), z (N*64)] fp32.
// R11: exact revert to R8 (measured best: 371.6us, reproduced twice).
// Locked decisions: CSR gather (not atomics); bf16 gather tables; R5 gather
// loop (32 lanes/edge, no unroll -- ILP variants regressed 2x); split-bf16
// MFMA encoder GEMMs; rcp-sigmoid; PLAIN decoder stores (nt/transposed/LDS-
// staged all regressed); separate scan/cnorm kernels.
// ---------------------------------------------------------------------------

typedef short short8 __attribute__((ext_vector_type(8)));
typedef short short4v __attribute__((ext_vector_type(4)));
typedef float f32x4 __attribute__((ext_vector_type(4)));

__device__ __forceinline__ float bf2f(short s) {
  unsigned int u = ((unsigned int)(unsigned short)s) << 16;
  return __uint_as_float(u);
}
__device__ __forceinline__ short f2bf(float f) {
  __hip_bfloat16 h = __float2bfloat16(f);
  return *reinterpret_cast<short*>(&h);
}

__global__ void k_deg(const int* __restrict__ src, const int* __restrict__ dst,
                      float* __restrict__ cs, float* __restrict__ cd, int E) {
  int i = blockIdx.x * blockDim.x + threadIdx.x;
  if (i < E) {
    atomicAdd(&cs[src[i]], 1.0f);
    atomicAdd(&cd[dst[i]], 1.0f);
  }
}

// Exclusive prefix sum of in-degree counts -> off[0..n]. Single block.
__global__ void __launch_bounds__(256) k_scan(const float* __restrict__ cnt,
                                              int* __restrict__ off, int n) {
  __shared__ int sums[256];
  const int t = threadIdx.x;
  const int per = n / 256;
  const int base = t * per;
  int s = 0;
  for (int i = 0; i < per; ++i) s += (int)cnt[base + i];
  sums[t] = s;
  __syncthreads();
  for (int d = 1; d < 256; d <<= 1) {
    int v = (t >= d) ? sums[t - d] : 0;
    __syncthreads();
    sums[t] += v;
    __syncthreads();
  }
  int run = t ? sums[t - 1] : 0;
  for (int i = 0; i < per; ++i) { off[base + i] = run; run += (int)cnt[base + i]; }
  if (t == 255) off[n] = run;
}

__global__ void k_cnorm(float* __restrict__ cs, float* __restrict__ cd, int n) {
  int i = blockIdx.x * blockDim.x + threadIdx.x;
  if (i < n) {
    float a = cs[i]; cs[i] = (a > 0.f) ? rsqrtf(a) : 0.f;
    float b = cd[i]; cd[i] = (b > 0.f) ? rsqrtf(b) : 0.f;
  }
}

// elist[off[d] + pos] = src, grouped by dst.
__global__ void k_fill(const int* __restrict__ src, const int* __restrict__ dst,
                       const int* __restrict__ off, int* __restrict__ cursor,
                       int* __restrict__ elist, int E) {
  int e = blockIdx.x * blockDim.x + threadIdx.x;
  if (e < E) {
    int d = dst[e];
    int pos = atomicAdd(&cursor[d], 1);
    elist[off[d] + pos] = src[e];
  }
}

// Merged weight prep: blocks [0,128) -> W1 transpose-split, [128,192) -> W2.
__global__ void k_wprep(const float* __restrict__ W1, const float* __restrict__ Wm,
                        const float* __restrict__ Ws,
                        short* __restrict__ w1hi, short* __restrict__ w1lo,
                        short* __restrict__ w2hi, short* __restrict__ w2lo) {
  if (blockIdx.x < 128) {
    int idx = blockIdx.x * 256 + threadIdx.x;  // 32768
    int c = idx >> 8, k = idx & 255;
    float v = W1[k * 128 + c];
    short hb = f2bf(v);
    float hf = bf2f(hb);
    w1hi[c * 256 + k] = hb;
    w1lo[c * 256 + k] = f2bf(v - hf);
  } else {
    int idx = (blockIdx.x - 128) * 256 + threadIdx.x;  // 16384
    int c = idx >> 7, k = idx & 127;
    float v = (c < 64) ? Wm[k * 64 + c] : Ws[k * 64 + (c - 64)];
    short hb = f2bf(v);
    float hf = bf2f(hb);
    w2hi[c * 128 + k] = hb;
    w2lo[c * 128 + k] = f2bf(v - hf);
  }
}

// bufA = (x * cs) @ W1 via split-bf16 MFMA, output bf16. Block: 64 rows x
// 128 cols, 4 waves (32 cols each), K=256 in 8 steps of 32.
__global__ void __launch_bounds__(256) k_enc1(const float* __restrict__ x,
                                              const short* __restrict__ wt_hi,
                                              const short* __restrict__ wt_lo,
                                              const float* __restrict__ cs,
                                              __hip_bfloat16* __restrict__ out) {
  const int wave = threadIdx.x >> 6, lane = threadIdx.x & 63;
  const int lrow = lane & 15, kq = lane >> 4;
  const int brow = blockIdx.x * 64;
  const int bcol = wave * 32;

  f32x4 acc[4][2];
#pragma unroll
  for (int i = 0; i < 4; ++i)
#pragma unroll
    for (int j = 0; j < 2; ++j) acc[i][j] = (f32x4){0.f, 0.f, 0.f, 0.f};

  float crow[4];
#pragma unroll
  for (int i = 0; i < 4; ++i) crow[i] = cs[brow + i * 16 + lrow];

  for (int ks = 0; ks < 8; ++ks) {
    short8 ahi[4], alo[4];
#pragma unroll
    for (int i = 0; i < 4; ++i) {
      const float* ap = x + (size_t)(brow + i * 16 + lrow) * 256 + ks * 32 + kq * 8;
      f32x4 a0 = *reinterpret_cast<const f32x4*>(ap);
      f32x4 a1 = *reinterpret_cast<const f32x4*>(ap + 4);
      const float c = crow[i];
      float vals[8] = {a0.x, a0.y, a0.z, a0.w, a1.x, a1.y, a1.z, a1.w};
      short8 h, l;
#pragma unroll
      for (int j = 0; j < 8; ++j) {
        float v = vals[j] * c;
        short hb = f2bf(v);
        h[j] = hb;
        l[j] = f2bf(v - bf2f(hb));
      }
      ahi[i] = h; alo[i] = l;
    }
    short8 bhi[2], blo[2];
#pragma unroll
    for (int j = 0; j < 2; ++j) {
      size_t boff = (size_t)(bcol + j * 16 + lrow) * 256 + ks * 32 + kq * 8;
      bhi[j] = *reinterpret_cast<const short8*>(wt_hi + boff);
      blo[j] = *reinterpret_cast<const short8*>(wt_lo + boff);
    }
#pragma unroll
    for (int i = 0; i < 4; ++i)
#pragma unroll
      for (int j = 0; j < 2; ++j) {
        acc[i][j] = __builtin_amdgcn_mfma_f32_16x16x32_bf16(ahi[i], bhi[j], acc[i][j], 0, 0, 0);
        acc[i][j] = __builtin_amdgcn_mfma_f32_16x16x32_bf16(ahi[i], blo[j], acc[i][j], 0, 0, 0);
        acc[i][j] = __builtin_amdgcn_mfma_f32_16x16x32_bf16(alo[i], bhi[j], acc[i][j], 0, 0, 0);
      }
  }
#pragma unroll
  for (int i = 0; i < 4; ++i)
#pragma unroll
    for (int r = 0; r < 4; ++r) {
      int row = brow + i * 16 + kq * 4 + r;
#pragma unroll
      for (int j = 0; j < 2; ++j)
        out[(size_t)row * 128 + bcol + j * 16 + lrow] = __float2bfloat16(acc[i][j][r]);
    }
}

// Layer-1 CSR gather (bf16 table), R5 structure. 32 lanes/edge, 8B/lane,
// 2 edges/wave-iter. hs = bf16(relu(agg*cd + b1) * cs).
__global__ void __launch_bounds__(256) k_gather1(const short* __restrict__ tmp,
                                                 const int* __restrict__ off,
                                                 const int* __restrict__ elist,
                                                 const float* __restrict__ cd,
                                                 const float* __restrict__ cs,
                                                 const float* __restrict__ b,
                                                 short* __restrict__ hs) {
  const int node = blockIdx.x * 4 + (threadIdx.x >> 6);
  const int lane = threadIdx.x & 63;
  const int half = lane >> 5;
  const int c4 = (lane & 31) << 2;
  const int e0 = off[node], e1 = off[node + 1];
  f32x4 a = {0.f, 0.f, 0.f, 0.f};
  for (int e = e0 + half; e < e1; e += 2) {
    short4v v = *reinterpret_cast<const short4v*>(tmp + (size_t)elist[e] * 128 + c4);
    a.x += bf2f(v[0]); a.y += bf2f(v[1]); a.z += bf2f(v[2]); a.w += bf2f(v[3]);
  }
  a.x += __shfl_xor(a.x, 32);
  a.y += __shfl_xor(a.y, 32);
  a.z += __shfl_xor(a.z, 32);
  a.w += __shfl_xor(a.w, 32);
  if (half == 0) {
    const float c = cd[node], s = cs[node];
    f32x4 bb = *reinterpret_cast<const f32x4*>(b + c4);
    short4v r;
    r[0] = f2bf(fmaxf(a.x * c + bb.x, 0.f) * s);
    r[1] = f2bf(fmaxf(a.y * c + bb.y, 0.f) * s);
    r[2] = f2bf(fmaxf(a.z * c + bb.z, 0.f) * s);
    r[3] = f2bf(fmaxf(a.w * c + bb.w, 0.f) * s);
    *reinterpret_cast<short4v*>(hs + (size_t)node * 128 + c4) = r;
  }
}

// Layer-2/3 shared aggregation: s2c[node] = cd[node] * sum_{src} hs[src].
__global__ void __launch_bounds__(256) k_gather2(const short* __restrict__ hs,
                                                 const int* __restrict__ off,
                                                 const int* __restrict__ elist,
                                                 const float* __restrict__ cd,
                                                 float* __restrict__ s2c) {
  const int node = blockIdx.x * 4 + (threadIdx.x >> 6);
  const int lane = threadIdx.x & 63;
  const int half = lane >> 5;
  const int c4 = (lane & 31) << 2;
  const int e0 = off[node], e1 = off[node + 1];
  f32x4 a = {0.f, 0.f, 0.f, 0.f};
  for (int e = e0 + half; e < e1; e += 2) {
    short4v v = *reinterpret_cast<const short4v*>(hs + (size_t)elist[e] * 128 + c4);
    a.x += bf2f(v[0]); a.y += bf2f(v[1]); a.z += bf2f(v[2]); a.w += bf2f(v[3]);
  }
  a.x += __shfl_xor(a.x, 32);
  a.y += __shfl_xor(a.y, 32);
  a.z += __shfl_xor(a.z, 32);
  a.w += __shfl_xor(a.w, 32);
  if (half == 0) {
    const float c = cd[node];
    *reinterpret_cast<f32x4*>(s2c + (size_t)node * 128 + c4) = a * c;
  }
}

// z-finish via split-bf16 MFMA: ys = s2c @ [Wm|Ws] + [bm|bs], then
// z = ys[:, :64] + noise * exp(ys[:, 64:]); also bf16 copy of z.
__global__ void __launch_bounds__(256) k_zfin2(const float* __restrict__ s2c,
                                               const short* __restrict__ wt_hi,
                                               const short* __restrict__ wt_lo,
                                               const float* __restrict__ bm,
                                               const float* __restrict__ bs,
                                               const float* __restrict__ noise,
                                               float* __restrict__ z,
                                               __hip_bfloat16* __restrict__ zb) {
  __shared__ float ys[64][128];
  const int wave = threadIdx.x >> 6, lane = threadIdx.x & 63;
  const int lrow = lane & 15, kq = lane >> 4;
  const int brow = blockIdx.x * 64;
  const int bcol = wave * 32;

  f32x4 acc[4][2];
#pragma unroll
  for (int i = 0; i < 4; ++i)
#pragma unroll
    for (int j = 0; j < 2; ++j) acc[i][j] = (f32x4){0.f, 0.f, 0.f, 0.f};

  for (int ks = 0; ks < 4; ++ks) {
    short8 ahi[4], alo[4];
#pragma unroll
    for (int i = 0; i < 4; ++i) {
      const float* ap = s2c + (size_t)(brow + i * 16 + lrow) * 128 + ks * 32 + kq * 8;
      f32x4 a0 = *reinterpret_cast<const f32x4*>(ap);
      f32x4 a1 = *reinterpret_cast<const f32x4*>(ap + 4);
      float vals[8] = {a0.x, a0.y, a0.z, a0.w, a1.x, a1.y, a1.z, a1.w};
      short8 h, l;
#pragma unroll
      for (int j = 0; j < 8; ++j) {
        float v = vals[j];
        short hb = f2bf(v);
        h[j] = hb;
        l[j] = f2bf(v - bf2f(hb));
      }
      ahi[i] = h; alo[i] = l;
    }
    short8 bhi[2], blo[2];
#pragma unroll
    for (int j = 0; j < 2; ++j) {
      size_t boff = (size_t)(bcol + j * 16 + lrow) * 128 + ks * 32 + kq * 8;
      bhi[j] = *reinterpret_cast<const short8*>(wt_hi + boff);
      blo[j] = *reinterpret_cast<const short8*>(wt_lo + boff);
    }
#pragma unroll
    for (int i = 0; i < 4; ++i)
#pragma unroll
      for (int j = 0; j < 2; ++j) {
        acc[i][j] = __builtin_amdgcn_mfma_f32_16x16x32_bf16(ahi[i], bhi[j], acc[i][j], 0, 0, 0);
        acc[i][j] = __builtin_amdgcn_mfma_f32_16x16x32_bf16(ahi[i], blo[j], acc[i][j], 0, 0, 0);
        acc[i][j] = __builtin_amdgcn_mfma_f32_16x16x32_bf16(alo[i], bhi[j], acc[i][j], 0, 0, 0);
      }
  }
#pragma unroll
  for (int j = 0; j < 2; ++j) {
    const int col = bcol + j * 16 + lrow;
    const float bias = (col < 64) ? bm[col] : bs[col - 64];
#pragma unroll
    for (int i = 0; i < 4; ++i)
#pragma unroll
      for (int r = 0; r < 4; ++r)
        ys[i * 16 + kq * 4 + r][col] = acc[i][j][r] + bias;
  }
  __syncthreads();
  const int t = threadIdx.x;
#pragma unroll
  for (int q = 0; q < 16; ++q) {
    int idx = t + 256 * q;  // 0..4095
    int row = idx >> 6, c = idx & 63;
    float m = ys[row][c], ls = ys[row][c + 64];
    float zv = m + noise[(size_t)(brow + row) * 64 + c] * __expf(ls);
    z[(size_t)(brow + row) * 64 + c]  = zv;
    zb[(size_t)(brow + row) * 64 + c] = __float2bfloat16(zv);
  }
}

// pre[i,j] = sigmoid(dot(z[i,:], z[j,:])) via mfma_f32_16x16x32_bf16.
__global__ void __launch_bounds__(256) k_zz_mfma(const short* __restrict__ zb,
                                                 float* __restrict__ pre, int n) {
  const int wave = threadIdx.x >> 6, lane = threadIdx.x & 63;
  const int wr = wave >> 1, wc = wave & 1;
  const int brow = blockIdx.y * 128 + wr * 64;
  const int bcol = blockIdx.x * 128 + wc * 64;
  const int lrow = lane & 15;
  const int kq = lane >> 4;

  short8 afrag[2][4], bfrag[2][4];
#pragma unroll
  for (int tt = 0; tt < 4; ++tt) {
#pragma unroll
    for (int ks = 0; ks < 2; ++ks) {
      afrag[ks][tt] = *reinterpret_cast<const short8*>(
          zb + (size_t)(brow + tt * 16 + lrow) * 64 + ks * 32 + kq * 8);
      bfrag[ks][tt] = *reinterpret_cast<const short8*>(
          zb + (size_t)(bcol + tt * 16 + lrow) * 64 + ks * 32 + kq * 8);
    }
  }

  f32x4 acc[4][4];
#pragma unroll
  for (int i = 0; i < 4; ++i)
#pragma unroll
    for (int j = 0; j < 4; ++j) acc[i][j] = (f32x4){0.f, 0.f, 0.f, 0.f};

#pragma unroll
  for (int i = 0; i < 4; ++i)
#pragma unroll
    for (int j = 0; j < 4; ++j) {
      acc[i][j] = __builtin_amdgcn_mfma_f32_16x16x32_bf16(afrag[0][i], bfrag[0][j], acc[i][j], 0, 0, 0);
      acc[i][j] = __builtin_amdgcn_mfma_f32_16x16x32_bf16(afrag[1][i], bfrag[1][j], acc[i][j], 0, 0, 0);
    }

  const int crow0 = kq * 4;
#pragma unroll
  for (int i = 0; i < 4; ++i) {
#pragma unroll
    for (int r = 0; r < 4; ++r) {
      size_t rowoff = (size_t)(brow + i * 16 + crow0 + r) * (size_t)n;
#pragma unroll
      for (int j = 0; j < 4; ++j) {
        float e = __expf(-acc[i][j][r]);
        pre[rowoff + bcol + j * 16 + lrow] = __builtin_amdgcn_rcpf(1.f + e);
      }
    }
  }
}

extern "C" void kernel_launch(void* const* d_in, const int* in_sizes, int n_in,
                              void* d_out, int out_size, void* d_ws, size_t ws_size,
                              hipStream_t stream) {
  const float* feat  = (const float*)d_in[0];
  const float* W1    = (const float*)d_in[1];
  const float* b1    = (const float*)d_in[2];
  const float* Wm    = (const float*)d_in[3];
  const float* bm    = (const float*)d_in[4];
  const float* Ws    = (const float*)d_in[5];
  const float* bs    = (const float*)d_in[6];
  const float* noise = (const float*)d_in[7];
  const int* esrc    = (const int*)d_in[8];
  const int* edst    = (const int*)d_in[9];

  const int N = in_sizes[0] / 256;   // 16384
  const int E = in_sizes[8];         // 262144

  float* out = (float*)d_out;
  float* z   = out + (size_t)N * N;  // z lives in d_out after pre

  char* ws = (char*)d_ws;
  float* c_src  = (float*)(ws + 0);                 // [N]
  float* c_dst  = (float*)(ws + 65536);             // [N]
  int*   cursor = (int*)  (ws + 131072);            // [N]
  int*   off    = (int*)  (ws + 196608);            // [N+1]
  int*   elist  = (int*)  (ws + 327680);            // [E] -> ends 1376256
  short* w1t_hi = (short*)(ws + 1376256);           // [128][256]
  short* w1t_lo = (short*)(ws + 1441792);
  short* w2t_hi = (short*)(ws + 1507328);           // [128][128]
  short* w2t_lo = (short*)(ws + 1540096);           // ends 1572864
  short* bufA   = (short*)(ws + 2097152);           // [N][128] bf16 xw1 out
  short* hsb    = (short*)(ws + 6291456);           // [N][128] bf16 relu(h)*cs
  float* s2c    = (float*)(ws + 10485760);          // [N][128] fp32
  __hip_bfloat16* zb = (__hip_bfloat16*)(ws + 18874368);  // [N,64] bf16 z

  // weight prep (independent of graph build)
  k_wprep<<<192, 256, 0, stream>>>(W1, Wm, Ws, w1t_hi, w1t_lo, w2t_hi, w2t_lo);

  // degree counts + CSR offsets + norms + edge lists
  hipMemsetAsync(ws, 0, 196608, stream);  // c_src, c_dst, cursor
  k_deg<<<(E + 255) / 256, 256, 0, stream>>>(esrc, edst, c_src, c_dst, E);
  k_scan<<<1, 256, 0, stream>>>(c_dst, off, N);
  k_cnorm<<<(N + 255) / 256, 256, 0, stream>>>(c_src, c_dst, N);
  k_fill<<<(E + 255) / 256, 256, 0, stream>>>(esrc, edst, off, cursor, elist, E);

  // layer 1: bufA = bf16((x*cs)@W1) ; gather -> hsb = bf16(relu(agg*cd+b1)*cs)
  k_enc1<<<N / 64, 256, 0, stream>>>(feat, w1t_hi, w1t_lo, c_src, (__hip_bfloat16*)bufA);
  k_gather1<<<N / 4, 256, 0, stream>>>(bufA, off, elist, c_dst, c_src, b1, hsb);

  // layers 2+3: s2c = cd * agg(hsb) ; z = GEMM + reparam
  k_gather2<<<N / 4, 256, 0, stream>>>(hsb, off, elist, c_dst, s2c);
  k_zfin2<<<N / 64, 256, 0, stream>>>(s2c, w2t_hi, w2t_lo, bm, bs, noise, z, zb);

  // decoder: pre = sigmoid(z @ z.T), bf16 MFMA
  dim3 zgrid(N / 128, N / 128);
  k_zz_mfma<<<zgrid, 256, 0, stream>>>((const short*)zb, out, N);
}